// Round 4
// baseline (1857.208 us; speedup 1.0000x reference)
//
#include <hip/hip_runtime.h>
#include <hip/hip_bf16.h>

typedef unsigned short u16;

struct EdgePtrs { const int* e[8]; };

// ---------------- kernel 0: zero the degree counters (graph-capture-safe memset)
__global__ __launch_bounds__(256) void CSGDN_32031866093637_kernel(int* __restrict__ p,
                                                                   int count) {
  int i = blockIdx.x * 256 + threadIdx.x;
  if (i < count) p[i] = 0;
}

// ---------------- kernel 1: H[p] = x @ W[p]; s[p] = H[p]@a_src[p]; d[p] = H[p]@a_dst[p]
__global__ __launch_bounds__(256) void gemm_kernel(
    const float* __restrict__ x, const float* __restrict__ W,
    const float* __restrict__ a_src, const float* __restrict__ a_dst,
    float* __restrict__ H, float* __restrict__ sv, float* __restrict__ dv, int n) {
  int p = blockIdx.y;
  int lane = threadIdx.x & 63;
  int wv = threadIdx.x >> 6;
  int row = blockIdx.x * 4 + wv;
  __shared__ float Wl[64 * 64];
  for (int i = threadIdx.x; i < 64 * 64; i += 256) Wl[i] = W[p * 4096 + i];
  __syncthreads();
  if (row >= n) return;
  float xv = x[(size_t)row * 64 + lane];
  float h = 0.f;
#pragma unroll
  for (int k = 0; k < 64; k++) {
    float xk = __shfl(xv, k, 64);          // unrolled const lane -> v_readlane
    h = fmaf(xk, Wl[k * 64 + lane], h);    // consecutive lanes, 2-way bank alias = free
  }
  H[(size_t)p * n * 64 + (size_t)row * 64 + lane] = h;
  float ssum = h * a_src[p * 64 + lane];
  float dsum = h * a_dst[p * 64 + lane];
#pragma unroll
  for (int o = 32; o; o >>= 1) {
    ssum += __shfl_xor(ssum, o, 64);
    dsum += __shfl_xor(dsum, o, 64);
  }
  if (lane == 0) { sv[p * n + row] = ssum; dv[p * n + row] = dsum; }
}

// ---------------- kernel 2: per-dst in-degree (self edges excluded; ref masks them to -1e9 -> weight 0)
__global__ __launch_bounds__(256) void count_kernel(EdgePtrs ep, int* __restrict__ cnt,
                                                    int E, int n) {
  int set = blockIdx.y;
  int i = blockIdx.x * 256 + threadIdx.x;
  if (i >= E) return;
  const int* e = ep.e[set];
  int s = e[i], d = e[E + i];
  if (s != d) atomicAdd(&cnt[(size_t)set * n + d], 1);
}

// ---------------- kernel 3: exclusive scan per set (one wave per set, shuffle scan)
__global__ __launch_bounds__(64) void scan_kernel(const int* __restrict__ cnt,
                                                  int* __restrict__ offs,
                                                  int* __restrict__ offs_w, int n) {
  int set = blockIdx.x;
  int lane = threadIdx.x;
  const int* c = cnt + (size_t)set * n;
  int* o = offs + (size_t)set * n;
  int* ow = offs_w + (size_t)set * n;
  int carry = 0;
  for (int base = 0; base < n; base += 64) {
    int i = base + lane;
    int v = (i < n) ? c[i] : 0;
    int x = v;
#pragma unroll
    for (int off = 1; off < 64; off <<= 1) {
      int y = __shfl_up(x, off, 64);
      if (lane >= off) x += y;
    }
    int excl = carry + x - v;
    if (i < n) { o[i] = excl; ow[i] = excl; }
    carry += __shfl(x, 63, 64);
  }
}

// ---------------- kernel 4: scatter src ids into CSR slots; offs_w becomes end offsets
__global__ __launch_bounds__(256) void scatter_kernel(EdgePtrs ep, int* __restrict__ offs_w,
                                                      u16* __restrict__ csr, int E, int n) {
  int set = blockIdx.y;
  int i = blockIdx.x * 256 + threadIdx.x;
  if (i >= E) return;
  const int* e = ep.e[set];
  int s = e[i], d = e[E + i];
  if (s != d) {
    int pos = atomicAdd(&offs_w[(size_t)set * n + d], 1);
    csr[(size_t)set * E + pos] = (u16)s;
  }
}

// ---------------- kernel 5: per-node segment softmax + aggregation (one wave per node)
__global__ __launch_bounds__(256) void gather_kernel(
    const u16* __restrict__ csr, const int* __restrict__ offs,
    const int* __restrict__ offs_w, const float* __restrict__ H,
    const float* __restrict__ sv, const float* __restrict__ dv,
    const float* __restrict__ bias, float* __restrict__ out, int E, int n) {
  // input set order: tp_a,tp_b,tn_a,tn_b,dp_a,dp_b,dn_a,dn_b
  // output order:    tp_a,tp_b,dp_a,dp_b,tn_a,tn_b,dn_a,dn_b
  const int omap[8] = {0, 1, 4, 5, 2, 3, 6, 7};
  int set = blockIdx.y;
  int p = set >> 1;
  int lane = threadIdx.x & 63;
  int wv = threadIdx.x >> 6;
  int node = blockIdx.x * 4 + wv;
  if (node >= n) return;
  int start = offs[(size_t)set * n + node];
  int end = offs_w[(size_t)set * n + node];
  const float* Hp = H + (size_t)p * n * 64;
  const float* sp = sv + (size_t)p * n;
  float di = dv[(size_t)p * n + node];
  float si = sp[node];
  float e_self = si + di;
  e_self = (e_self > 0.f) ? e_self : 0.2f * e_self;
  // phase 1: segment max (self-loop participates; masked self-edges excluded,
  // matches ref since expf(-1e9 - m) == 0 in f32)
  float m = e_self;
  for (int j = start + lane; j < end; j += 64) {
    int sj = csr[(size_t)set * E + j];
    float e = sp[sj] + di;
    e = (e > 0.f) ? e : 0.2f * e;
    m = fmaxf(m, e);
  }
#pragma unroll
  for (int o = 32; o; o >>= 1) m = fmaxf(m, __shfl_xor(m, o, 64));
  // phase 2: chunked exp + broadcast accumulate
  float acc = 0.f, denom = 0.f;
  for (int base = start; base < end; base += 64) {
    int j = base + lane;
    float pj = 0.f;
    int sj = 0;
    if (j < end) {
      sj = csr[(size_t)set * E + j];
      float e = sp[sj] + di;
      e = (e > 0.f) ? e : 0.2f * e;
      pj = __expf(e - m);
    }
    int cntc = min(64, end - base);
    for (int t = 0; t < cntc; t++) {
      float pt = __shfl(pj, t, 64);
      int st = __shfl(sj, t, 64);
      acc = fmaf(pt, Hp[(size_t)st * 64 + lane], acc);
      denom += pt;
    }
  }
  // self loop
  float pself = __expf(e_self - m);
  acc = fmaf(pself, Hp[(size_t)node * 64 + lane], acc);
  denom += pself;
  float o = acc / denom + bias[p * 64 + lane];
  o = fmaxf(o, 0.f);
  out[(size_t)omap[set] * n * 64 + (size_t)node * 64 + lane] = o;
}

extern "C" void kernel_launch(void* const* d_in, const int* in_sizes, int n_in,
                              void* d_out, int out_size, void* d_ws, size_t ws_size,
                              hipStream_t stream) {
  const int E = in_sizes[0] / 2;
  const int n = in_sizes[8] / 64;
  const float* x = (const float*)d_in[8];
  const float* W = (const float*)d_in[9];
  const float* a_src = (const float*)d_in[10];
  const float* a_dst = (const float*)d_in[11];
  const float* bias = (const float*)d_in[12];
  float* out = (float*)d_out;

  char* ws = (char*)d_ws;
  auto alloc = [&](size_t bytes) {
    char* p = ws;
    ws += (bytes + 255) & ~(size_t)255;
    return p;
  };
  float* H = (float*)alloc((size_t)4 * n * 64 * 4);      // 51.2 MB
  float* sv = (float*)alloc((size_t)4 * n * 4);
  float* dv = (float*)alloc((size_t)4 * n * 4);
  int* cnt = (int*)alloc((size_t)8 * n * 4);
  int* offs = (int*)alloc((size_t)8 * n * 4);
  int* offs_w = (int*)alloc((size_t)8 * n * 4);
  u16* csr = (u16*)alloc((size_t)8 * E * 2);             // 12.8 MB

  EdgePtrs ep;
  for (int i = 0; i < 8; i++) ep.e[i] = (const int*)d_in[i];

  dim3 b256(256);
  CSGDN_32031866093637_kernel<<<(8 * n + 255) / 256, b256, 0, stream>>>(cnt, 8 * n);
  gemm_kernel<<<dim3((n + 3) / 4, 4), b256, 0, stream>>>(x, W, a_src, a_dst, H, sv, dv, n);
  count_kernel<<<dim3((E + 255) / 256, 8), b256, 0, stream>>>(ep, cnt, E, n);
  scan_kernel<<<8, 64, 0, stream>>>(cnt, offs, offs_w, n);
  scatter_kernel<<<dim3((E + 255) / 256, 8), b256, 0, stream>>>(ep, offs_w, csr, E, n);
  gather_kernel<<<dim3((n + 3) / 4, 8), b256, 0, stream>>>(csr, offs, offs_w, H, sv, dv,
                                                           bias, out, E, n);
}